// Round 11
// baseline (437.704 us; speedup 1.0000x reference)
//
#include <hip/hip_runtime.h>

// MultiheadAttentionWithBias: B=2, L=2048, D=1024, H=16, HD=64
// cvt_all -> QKV GEMM (V^T fused epilogue) -> flash attn (32x32 swapped QK^T,
// fixed-max softmax, in-register P, 2-WAY K-SPLIT in-block: 8 waves = 4 q-strips
// x 2 k-halves, partials add exactly under fixed max; dbuf LDS, counted vmcnt,
// XCD swizzle) -> out GEMM.
// R11: occupancy fix (R10 counters: 22.7% grid-limited, all pipes idle).

typedef __attribute__((ext_vector_type(8))) short bf16x8;
typedef __attribute__((ext_vector_type(4))) float f32x4;
typedef __attribute__((ext_vector_type(16))) float f32x16;
typedef __attribute__((ext_vector_type(8))) unsigned short u16x8;
using u16 = unsigned short;

#define MFMA16(a, b, c) __builtin_amdgcn_mfma_f32_16x16x32_bf16((a), (b), (c), 0, 0, 0)
#define MFMA32(a, b, c) __builtin_amdgcn_mfma_f32_32x32x16_bf16((a), (b), (c), 0, 0, 0)
#define LOG2E 1.44269504088896f
#define QSCALE (0.125f * 1.44269504088896f)

__device__ __forceinline__ u16 f2bf(float f) {
  union { float f; unsigned int u; } v; v.f = f;
  unsigned int r = v.u + 0x7FFFu + ((v.u >> 16) & 1u);
  return (u16)(r >> 16);
}

__device__ __forceinline__ unsigned cvt_pk_bf16(float lo, float hi) {
  unsigned r;
  asm volatile("v_cvt_pk_bf16_f32 %0, %1, %2" : "=v"(r) : "v"(lo), "v"(hi));
  return r;
}

// a' = {a.lanes0-31, b.lanes0-31}; b' = {a.lanes32-63, b.lanes32-63}
__device__ __forceinline__ void pl32swap(unsigned& a, unsigned& b) {
#if __has_builtin(__builtin_amdgcn_permlane32_swap)
  typedef unsigned pl2 __attribute__((ext_vector_type(2)));
  pl2 r = __builtin_amdgcn_permlane32_swap(a, b, false, false);
  a = r[0];
  b = r[1];
#else
  asm volatile("v_permlane32_swap_b32 %0, %1" : "+v"(a), "+v"(b));
#endif
}

__device__ __forceinline__ void g2lds16(const void* gsrc, void* ldst) {
  __builtin_amdgcn_global_load_lds(
      (const __attribute__((address_space(1))) unsigned int*)gsrc,
      (__attribute__((address_space(3))) unsigned int*)ldst, 16, 0, 0);
}

// ---------------- merged f32 -> bf16 convert (x, Wq, Wk, Wv, Wo) ----------------
__global__ __launch_bounds__(256) void cvt_all(
    const float* __restrict__ x, const float* __restrict__ wq,
    const float* __restrict__ wk, const float* __restrict__ wv,
    const float* __restrict__ wo, u16* __restrict__ xb,
    u16* __restrict__ w1b, u16* __restrict__ wob) {
  int bid = blockIdx.x, tid = threadIdx.x;
  const float* src; u16* dst; int i;
  if (bid < 2048)      { src = x;  dst = xb;            i = bid * 256 + tid; }
  else if (bid < 2560) { src = wq; dst = w1b;           i = (bid - 2048) * 256 + tid; }
  else if (bid < 3072) { src = wk; dst = w1b + (1<<20); i = (bid - 2560) * 256 + tid; }
  else if (bid < 3584) { src = wv; dst = w1b + (2<<20); i = (bid - 3072) * 256 + tid; }
  else                 { src = wo; dst = wob;           i = (bid - 3584) * 256 + tid; }
  const float4* s = (const float4*)src;
  float4 a = s[2 * i], b = s[2 * i + 1];
  u16x8 o;
  o[0] = f2bf(a.x); o[1] = f2bf(a.y); o[2] = f2bf(a.z); o[3] = f2bf(a.w);
  o[4] = f2bf(b.x); o[5] = f2bf(b.y); o[6] = f2bf(b.z); o[7] = f2bf(b.w);
  ((u16x8*)dst)[i] = o;
}

// ---------------- GEMM C = A * B^T (unchanged, passing) ----------------
template <int MODE>
__global__ __launch_bounds__(256, 2) void gemm_bt(
    const u16* __restrict__ A, const u16* __restrict__ B,
    u16* __restrict__ qp, u16* __restrict__ kp, u16* __restrict__ vp,
    const float* __restrict__ b0, const float* __restrict__ b1,
    const float* __restrict__ b2, float* __restrict__ outp,
    const float* __restrict__ bo) {
  __shared__ __align__(16) u16 lA[128 * 64];
  __shared__ __align__(16) u16 lB[128 * 64];
  const int tid = threadIdx.x;
  const int lane = tid & 63, wid = tid >> 6;
  const int g = lane >> 4, cc = lane & 15;
  const int wr = wid >> 1, wc = wid & 1;
  const int m0 = blockIdx.y * 128, n0 = blockIdx.x * 128;
  f32x4 acc[4][4] = {};
  for (int kt = 0; kt < 16; ++kt) {
    const int kof = kt * 64;
#pragma unroll
    for (int i = 0; i < 4; ++i) {
      int cid = i * 256 + tid;
      int row = cid >> 3;
      int col = (cid & 7) * 8;
      g2lds16(A + (size_t)(m0 + row) * 1024 + kof + col, &lA[(i * 256 + wid * 64) * 8]);
      g2lds16(B + (size_t)(n0 + row) * 1024 + kof + col, &lB[(i * 256 + wid * 64) * 8]);
    }
    __syncthreads();
#pragma unroll
    for (int kc = 0; kc < 2; ++kc) {
      bf16x8 af[4], bfr[4];
#pragma unroll
      for (int mf = 0; mf < 4; ++mf)
        af[mf] = *(const bf16x8*)&lA[(wr * 64 + mf * 16 + cc) * 64 + kc * 32 + g * 8];
#pragma unroll
      for (int nf = 0; nf < 4; ++nf)
        bfr[nf] = *(const bf16x8*)&lB[(wc * 64 + nf * 16 + cc) * 64 + kc * 32 + g * 8];
#pragma unroll
      for (int mf = 0; mf < 4; ++mf)
#pragma unroll
        for (int nf = 0; nf < 4; ++nf)
          acc[mf][nf] = MFMA16(af[mf], bfr[nf], acc[mf][nf]);
    }
    __syncthreads();
  }
#pragma unroll
  for (int mf = 0; mf < 4; ++mf) {
#pragma unroll
    for (int nf = 0; nf < 4; ++nf) {
      int n = n0 + wc * 64 + nf * 16 + cc;
      if (MODE == 0) {
        int which = n >> 10;
        int nn = n & 1023;
        const float* bp = which == 0 ? b0 : (which == 1 ? b1 : b2);
        float bias = bp[nn];
        int h = nn >> 6, hd = nn & 63;
        int mb = m0 + wr * 64 + mf * 16 + g * 4;
        int bb = mb >> 11, ll0 = mb & 2047;
        if (which == 2) {
          ushort4 pk4;
          pk4.x = f2bf(acc[mf][nf][0] + bias);
          pk4.y = f2bf(acc[mf][nf][1] + bias);
          pk4.z = f2bf(acc[mf][nf][2] + bias);
          pk4.w = f2bf(acc[mf][nf][3] + bias);
          *(ushort4*)&vp[(((size_t)(bb * 16 + h)) * 64 + hd) * 2048 + ll0] = pk4;
        } else {
          u16* dp = which == 0 ? qp : kp;
#pragma unroll
          for (int r = 0; r < 4; ++r) {
            float val = acc[mf][nf][r] + bias;
            if (which == 0) val *= QSCALE;
            dp[(((size_t)(bb * 16 + h)) * 2048 + ll0 + r) * 64 + hd] = f2bf(val);
          }
        }
      } else {
        float bias = bo[n];
#pragma unroll
        for (int r = 0; r < 4; ++r) {
          int m = m0 + wr * 64 + mf * 16 + g * 4 + r;
          outp[(size_t)m * 1024 + n] = acc[mf][nf][r] + bias;
        }
      }
    }
  }
}

// ---------------- Flash attention: 2-way K-split, in-block combine -------------
// Block = 8 waves (512 thr) = 4 q-strips (32 rows) x 2 k-halves; 16 iters.
// Per iter: stage 4 tiles (K,V for both halves) dbuf; each wave computes its
// (q-strip, k-half). Fixed-max softmax -> partials add exactly at the end:
// half-1 waves dump O/lsum into the (dead) staging LDS; half-0 waves combine,
// normalize, write. Occupancy: 4096 waves = 16/CU = 4/SIMD (VGPR<=128).
__global__ __launch_bounds__(512, 4) void attn_kernel(
    const u16* __restrict__ qm, const u16* __restrict__ km,
    const u16* __restrict__ vtm, const float* __restrict__ bias,
    u16* __restrict__ aout) {
  __shared__ __align__(16) u16 smem[2][16384];  // dbuf x {K0,K1,V0,V1} x 8KB = 64KB
  const int tid = threadIdx.x;
  const int lane = tid & 63, wid = tid >> 6;
  const int lq = lane & 31, hi = lane >> 5;
  const int ws = wid & 3, hf = wid >> 2;  // q-strip, k-half
  // XCD swizzle: 512 blocks; xcd = lin&7 owns heads 2*xcd, 2*xcd+1
  const int lin = blockIdx.x;
  const int xcd = lin & 7, j = lin >> 3;  // j in [0,64)
  const int h = xcd * 2 + (j >> 5);
  const int rem = j & 31;
  const int b = rem >> 4, qb = rem & 15;
  const int q0w = qb * 128 + ws * 32;
  const size_t bh = (size_t)b * 16 + h;
  const u16* kg = km + bh * 2048 * 64;
  const u16* vg = vtm + bh * 64 * 2048;
  const u16* qbase = qm + (bh * 2048 + q0w) * 64;
  // lane's bias base: row (q0w+lq), col (hf*1024 + 4*hi)
  const float* brow = bias + ((size_t)h * 2048 + q0w + lq) * 2048 + hf * 1024 + 4 * hi;
  // this wave's K/V LDS tiles within buf P
  const int kofs = hf * 4096, vofs = 8192 + hf * 4096;

  bf16x8 qf[4];
#pragma unroll
  for (int i = 0; i < 4; ++i)
    qf[i] = *(const bf16x8*)&qbase[(size_t)lq * 64 + i * 16 + 8 * hi];

  f32x16 o[2];
#pragma unroll
  for (int r = 0; r < 16; ++r) { o[0][r] = 0.f; o[1][r] = 0.f; }
  float lsum = 0.f;

  // stage one 64x64 tile with 512 threads (1 g2lds each), pre-swizzled source
#define STAGE_TILE(gbase, rs, ldst)                                            \
  {                                                                            \
    int row = tid >> 3, pcol = tid & 7;                                        \
    int lcol = pcol ^ (row & 7);                                               \
    g2lds16((gbase) + (size_t)row * (rs) + lcol * 8, (ldst) + tid * 8);        \
  }

  // stage k-tile kt_ for both halves into buf P (4 g2lds per thread)
#define STAGE_ALL(P, kt_)                                                      \
  STAGE_TILE(kg + (size_t)((kt_) * 64) * 64, 64, &smem[P][0])                  \
  STAGE_TILE(kg + (size_t)(1024 + (kt_) * 64) * 64, 64, &smem[P][4096])        \
  STAGE_TILE(vg + (kt_) * 64, 2048, &smem[P][8192])                            \
  STAGE_TILE(vg + 1024 + (kt_) * 64, 2048, &smem[P][12288])

  // one 32-k subtile of this wave's half: QK^T(-32 acc) + bias + exp2 + PV
#define SUBTILE(s_, BC, PP)                                                    \
  {                                                                            \
    const u16* lKp = &smem[PP][kofs];                                          \
    const u16* lVp = &smem[PP][vofs];                                          \
    f32x16 acc;                                                                \
    _Pragma("unroll") for (int r = 0; r < 16; ++r) acc[r] = -32.0f;            \
    _Pragma("unroll") for (int i = 0; i < 4; ++i) {                            \
      int row = (s_) * 32 + lq;                                                \
      bf16x8 kf = *(const bf16x8*)&lKp[row * 64 + (((2 * i + hi) ^ (row & 7))) * 8]; \
      acc = MFMA32(kf, qf[i], acc);                                            \
    }                                                                          \
    _Pragma("unroll") for (int r = 0; r < 16; ++r)                             \
      acc[r] = fmaf(BC[(s_) * 4 + (r >> 2)][r & 3], LOG2E, acc[r]);            \
    float p[16];                                                               \
    _Pragma("unroll") for (int r = 0; r < 16; ++r) {                           \
      p[r] = __builtin_amdgcn_exp2f(acc[r]);                                   \
      lsum += p[r];                                                            \
    }                                                                          \
    unsigned c0 = cvt_pk_bf16(p[0], p[1]),   c1 = cvt_pk_bf16(p[2], p[3]);     \
    unsigned c2 = cvt_pk_bf16(p[4], p[5]),   c3 = cvt_pk_bf16(p[6], p[7]);     \
    unsigned c4 = cvt_pk_bf16(p[8], p[9]),   c5 = cvt_pk_bf16(p[10], p[11]);   \
    unsigned c6 = cvt_pk_bf16(p[12], p[13]), c7 = cvt_pk_bf16(p[14], p[15]);   \
    pl32swap(c0, c2); pl32swap(c1, c3);                                        \
    pl32swap(c4, c6); pl32swap(c5, c7);                                        \
    union { unsigned u[4]; bf16x8 v; } a0, a1;                                 \
    a0.u[0] = c0; a0.u[1] = c1; a0.u[2] = c2; a0.u[3] = c3;                    \
    a1.u[0] = c4; a1.u[1] = c5; a1.u[2] = c6; a1.u[3] = c7;                    \
    _Pragma("unroll") for (int dblk = 0; dblk < 2; ++dblk) {                   \
      int rowv = dblk * 32 + lq;                                               \
      bf16x8 v0 = *(const bf16x8*)&lVp[rowv * 64 + (((4 * (s_) + hi) ^ (rowv & 7))) * 8];     \
      bf16x8 v1 = *(const bf16x8*)&lVp[rowv * 64 + (((4 * (s_) + 2 + hi) ^ (rowv & 7))) * 8]; \
      o[dblk] = MFMA32(a0.v, v0, o[dblk]);                                     \
      o[dblk] = MFMA32(a1.v, v1, o[dblk]);                                     \
    }                                                                          \
  }

#define ATTN_STEP(kt_, BC, DOSTAGE, DOBIAS)                                    \
  {                                                                            \
    const int k0 = (kt_) * 64;                                                 \
    const int PP = (kt_) & 1;                                                  \
    if (DOSTAGE) { STAGE_ALL(PP ^ 1, (kt_) + 1) }                              \
    __builtin_amdgcn_sched_barrier(0);                                         \
    SUBTILE(0, BC, PP)                                                         \
    SUBTILE(1, BC, PP)                                                         \
    if (DOBIAS) {                                                              \
      _Pragma("unroll") for (int gi = 0; gi < 8; ++gi)                         \
          BC[gi] = *(const float4*)(brow + k0 + 128 + (gi >> 2) * 32 + (gi & 3) * 8); \
    }                                                                          \
    __builtin_amdgcn_sched_barrier(0);                                         \
    if (DOSTAGE && DOBIAS) { asm volatile("s_waitcnt vmcnt(8)" ::: "memory"); }\
    else                   { asm volatile("s_waitcnt vmcnt(0)" ::: "memory"); }\
    __builtin_amdgcn_sched_barrier(0);                                         \
    if (DOSTAGE) { __builtin_amdgcn_s_barrier(); }                             \
    __builtin_amdgcn_sched_barrier(0);                                         \
  }

  float4 bA[8], bB[8];
  // prologue: stage k-tile 0 (both halves) -> buf0, bias(0)->bA, bias(1)->bB
  STAGE_ALL(0, 0)
  __builtin_amdgcn_sched_barrier(0);
#pragma unroll
  for (int gi = 0; gi < 8; ++gi) {
    bA[gi] = *(const float4*)(brow + (gi >> 2) * 32 + (gi & 3) * 8);
    bB[gi] = *(const float4*)(brow + 64 + (gi >> 2) * 32 + (gi & 3) * 8);
  }
  __builtin_amdgcn_sched_barrier(0);
  asm volatile("s_waitcnt vmcnt(16)" ::: "memory");  // stage(0) landed
  __builtin_amdgcn_sched_barrier(0);
  __builtin_amdgcn_s_barrier();
  __builtin_amdgcn_sched_barrier(0);

#pragma unroll 1
  for (int kt = 0; kt < 14; kt += 2) {
    ATTN_STEP(kt, bA, 1, 1)
    ATTN_STEP(kt + 1, bB, 1, 1)
  }
  ATTN_STEP(14, bA, 1, 0)
  ATTN_STEP(15, bB, 0, 0)
#undef ATTN_STEP
#undef SUBTILE
#undef STAGE_ALL
#undef STAGE_TILE

  // ---- in-block combine (staging LDS is dead now) ----
  lsum += __shfl_xor(lsum, 32, 64);  // full half-sum for q=lq (both hi)
  __syncthreads();
  float* po = (float*)smem;          // 4 strips x 32 q x 64 d = 8192 f32
  float* pl = po + 8192;             // 4 strips x 32 q lsum
  if (hf == 1) {
#pragma unroll
    for (int r = 0; r < 16; ++r) {
      int qr = (r & 3) + 8 * (r >> 2) + 4 * hi;
      po[(ws * 32 + qr) * 64 + lq] = o[0][r];
      po[(ws * 32 + qr) * 64 + 32 + lq] = o[1][r];
    }
    pl[ws * 32 + lq] = lsum;  // hi=0/1 write same value
  }
  __syncthreads();
  if (hf == 0) {
    float l1 = pl[ws * 32 + lq];
    float linv = 1.0f / (lsum + l1);
#pragma unroll
    for (int r = 0; r < 16; ++r) {
      int qr = (r & 3) + 8 * (r >> 2) + 4 * hi;
      float lr = __shfl(linv, qr, 64);
      float v0 = o[0][r] + po[(ws * 32 + qr) * 64 + lq];
      float v1 = o[1][r] + po[(ws * 32 + qr) * 64 + 32 + lq];
      size_t base = ((size_t)b * 2048 + q0w + qr) * 1024 + h * 64 + lq;
      aout[base] = f2bf(v0 * lr);
      aout[base + 32] = f2bf(v1 * lr);
    }
  }
}

extern "C" void kernel_launch(void* const* d_in, const int* in_sizes, int n_in,
                              void* d_out, int out_size, void* d_ws, size_t ws_size,
                              hipStream_t stream) {
  const float* x  = (const float*)d_in[0];
  const float* rb = (const float*)d_in[1];
  const float* Wq = (const float*)d_in[2];
  const float* bq = (const float*)d_in[3];
  const float* Wk = (const float*)d_in[4];
  const float* bk = (const float*)d_in[5];
  const float* Wv = (const float*)d_in[6];
  const float* bv = (const float*)d_in[7];
  const float* Wo = (const float*)d_in[8];
  const float* bo = (const float*)d_in[9];
  float* out = (float*)d_out;
  char* ws = (char*)d_ws;

  u16* xb   = (u16*)(ws);                 // 8 MB  [4096,1024] bf16 (reused as aout)
  u16* W1b  = (u16*)(ws + (8 << 20));     // 6 MB  [3072,1024] bf16 (Wq|Wk|Wv)
  u16* Wob  = (u16*)(ws + (14 << 20));    // 2 MB  [1024,1024] bf16
  u16* qb   = (u16*)(ws + (16 << 20));    // 8 MB  [B,H,L,HD]
  u16* kb2  = (u16*)(ws + (24 << 20));    // 8 MB  [B,H,L,HD]
  u16* vtb  = (u16*)(ws + (32 << 20));    // 8 MB  [B,H,HD,L] (written by QKV GEMM)
  u16* aout = xb;                         // alias: xb dead after QKV GEMM

  cvt_all<<<4096, 256, 0, stream>>>(x, Wq, Wk, Wv, Wo, xb, W1b, Wob);
  gemm_bt<0><<<dim3(24, 32), 256, 0, stream>>>(xb, W1b, qb, kb2, vtb, bq, bk, bv,
                                               nullptr, nullptr);
  attn_kernel<<<512, 512, 0, stream>>>(qb, kb2, vtb, rb, aout);
  gemm_bt<1><<<dim3(8, 32), 256, 0, stream>>>(aout, Wob, nullptr, nullptr, nullptr,
                                              nullptr, nullptr, nullptr, out, bo);
}

// Round 12
// 172.981 us; speedup vs baseline: 2.5304x; 2.5304x over previous
//
#include <hip/hip_runtime.h>

// MultiheadAttentionWithBias: B=2, L=2048, D=1024, H=16, HD=64
// cvt_all -> QKV GEMM (V^T fused epilogue) -> flash attn (32x32 swapped QK^T,
// fixed-max softmax, in-register P, 2-way K-split in-block, dbuf LDS,
// counted vmcnt, XCD swizzle) -> out GEMM.
// R12 = R11 with the spill fixed: __launch_bounds__(512,2) (VGPR cap 128),
// bias depth-2 -> depth-1 split refill (-32 regs), exp2 in-place (-16 regs).

typedef __attribute__((ext_vector_type(8))) short bf16x8;
typedef __attribute__((ext_vector_type(4))) float f32x4;
typedef __attribute__((ext_vector_type(16))) float f32x16;
typedef __attribute__((ext_vector_type(8))) unsigned short u16x8;
using u16 = unsigned short;

#define MFMA16(a, b, c) __builtin_amdgcn_mfma_f32_16x16x32_bf16((a), (b), (c), 0, 0, 0)
#define MFMA32(a, b, c) __builtin_amdgcn_mfma_f32_32x32x16_bf16((a), (b), (c), 0, 0, 0)
#define LOG2E 1.44269504088896f
#define QSCALE (0.125f * 1.44269504088896f)

__device__ __forceinline__ u16 f2bf(float f) {
  union { float f; unsigned int u; } v; v.f = f;
  unsigned int r = v.u + 0x7FFFu + ((v.u >> 16) & 1u);
  return (u16)(r >> 16);
}

__device__ __forceinline__ unsigned cvt_pk_bf16(float lo, float hi) {
  unsigned r;
  asm volatile("v_cvt_pk_bf16_f32 %0, %1, %2" : "=v"(r) : "v"(lo), "v"(hi));
  return r;
}

// a' = {a.lanes0-31, b.lanes0-31}; b' = {a.lanes32-63, b.lanes32-63}
__device__ __forceinline__ void pl32swap(unsigned& a, unsigned& b) {
#if __has_builtin(__builtin_amdgcn_permlane32_swap)
  typedef unsigned pl2 __attribute__((ext_vector_type(2)));
  pl2 r = __builtin_amdgcn_permlane32_swap(a, b, false, false);
  a = r[0];
  b = r[1];
#else
  asm volatile("v_permlane32_swap_b32 %0, %1" : "+v"(a), "+v"(b));
#endif
}

__device__ __forceinline__ void g2lds16(const void* gsrc, void* ldst) {
  __builtin_amdgcn_global_load_lds(
      (const __attribute__((address_space(1))) unsigned int*)gsrc,
      (__attribute__((address_space(3))) unsigned int*)ldst, 16, 0, 0);
}

// ---------------- merged f32 -> bf16 convert (x, Wq, Wk, Wv, Wo) ----------------
__global__ __launch_bounds__(256) void cvt_all(
    const float* __restrict__ x, const float* __restrict__ wq,
    const float* __restrict__ wk, const float* __restrict__ wv,
    const float* __restrict__ wo, u16* __restrict__ xb,
    u16* __restrict__ w1b, u16* __restrict__ wob) {
  int bid = blockIdx.x, tid = threadIdx.x;
  const float* src; u16* dst; int i;
  if (bid < 2048)      { src = x;  dst = xb;            i = bid * 256 + tid; }
  else if (bid < 2560) { src = wq; dst = w1b;           i = (bid - 2048) * 256 + tid; }
  else if (bid < 3072) { src = wk; dst = w1b + (1<<20); i = (bid - 2560) * 256 + tid; }
  else if (bid < 3584) { src = wv; dst = w1b + (2<<20); i = (bid - 3072) * 256 + tid; }
  else                 { src = wo; dst = wob;           i = (bid - 3584) * 256 + tid; }
  const float4* s = (const float4*)src;
  float4 a = s[2 * i], b = s[2 * i + 1];
  u16x8 o;
  o[0] = f2bf(a.x); o[1] = f2bf(a.y); o[2] = f2bf(a.z); o[3] = f2bf(a.w);
  o[4] = f2bf(b.x); o[5] = f2bf(b.y); o[6] = f2bf(b.z); o[7] = f2bf(b.w);
  ((u16x8*)dst)[i] = o;
}

// ---------------- GEMM C = A * B^T (unchanged, passing) ----------------
template <int MODE>
__global__ __launch_bounds__(256, 2) void gemm_bt(
    const u16* __restrict__ A, const u16* __restrict__ B,
    u16* __restrict__ qp, u16* __restrict__ kp, u16* __restrict__ vp,
    const float* __restrict__ b0, const float* __restrict__ b1,
    const float* __restrict__ b2, float* __restrict__ outp,
    const float* __restrict__ bo) {
  __shared__ __align__(16) u16 lA[128 * 64];
  __shared__ __align__(16) u16 lB[128 * 64];
  const int tid = threadIdx.x;
  const int lane = tid & 63, wid = tid >> 6;
  const int g = lane >> 4, cc = lane & 15;
  const int wr = wid >> 1, wc = wid & 1;
  const int m0 = blockIdx.y * 128, n0 = blockIdx.x * 128;
  f32x4 acc[4][4] = {};
  for (int kt = 0; kt < 16; ++kt) {
    const int kof = kt * 64;
#pragma unroll
    for (int i = 0; i < 4; ++i) {
      int cid = i * 256 + tid;
      int row = cid >> 3;
      int col = (cid & 7) * 8;
      g2lds16(A + (size_t)(m0 + row) * 1024 + kof + col, &lA[(i * 256 + wid * 64) * 8]);
      g2lds16(B + (size_t)(n0 + row) * 1024 + kof + col, &lB[(i * 256 + wid * 64) * 8]);
    }
    __syncthreads();
#pragma unroll
    for (int kc = 0; kc < 2; ++kc) {
      bf16x8 af[4], bfr[4];
#pragma unroll
      for (int mf = 0; mf < 4; ++mf)
        af[mf] = *(const bf16x8*)&lA[(wr * 64 + mf * 16 + cc) * 64 + kc * 32 + g * 8];
#pragma unroll
      for (int nf = 0; nf < 4; ++nf)
        bfr[nf] = *(const bf16x8*)&lB[(wc * 64 + nf * 16 + cc) * 64 + kc * 32 + g * 8];
#pragma unroll
      for (int mf = 0; mf < 4; ++mf)
#pragma unroll
        for (int nf = 0; nf < 4; ++nf)
          acc[mf][nf] = MFMA16(af[mf], bfr[nf], acc[mf][nf]);
    }
    __syncthreads();
  }
#pragma unroll
  for (int mf = 0; mf < 4; ++mf) {
#pragma unroll
    for (int nf = 0; nf < 4; ++nf) {
      int n = n0 + wc * 64 + nf * 16 + cc;
      if (MODE == 0) {
        int which = n >> 10;
        int nn = n & 1023;
        const float* bp = which == 0 ? b0 : (which == 1 ? b1 : b2);
        float bias = bp[nn];
        int h = nn >> 6, hd = nn & 63;
        int mb = m0 + wr * 64 + mf * 16 + g * 4;
        int bb = mb >> 11, ll0 = mb & 2047;
        if (which == 2) {
          ushort4 pk4;
          pk4.x = f2bf(acc[mf][nf][0] + bias);
          pk4.y = f2bf(acc[mf][nf][1] + bias);
          pk4.z = f2bf(acc[mf][nf][2] + bias);
          pk4.w = f2bf(acc[mf][nf][3] + bias);
          *(ushort4*)&vp[(((size_t)(bb * 16 + h)) * 64 + hd) * 2048 + ll0] = pk4;
        } else {
          u16* dp = which == 0 ? qp : kp;
#pragma unroll
          for (int r = 0; r < 4; ++r) {
            float val = acc[mf][nf][r] + bias;
            if (which == 0) val *= QSCALE;
            dp[(((size_t)(bb * 16 + h)) * 2048 + ll0 + r) * 64 + hd] = f2bf(val);
          }
        }
      } else {
        float bias = bo[n];
#pragma unroll
        for (int r = 0; r < 4; ++r) {
          int m = m0 + wr * 64 + mf * 16 + g * 4 + r;
          outp[(size_t)m * 1024 + n] = acc[mf][nf][r] + bias;
        }
      }
    }
  }
}

// ---------------- Flash attention: 2-way K-split, spill-free -------------------
// Block = 8 waves (512 thr) = 4 q-strips (32 rows) x 2 k-halves; 16 iters.
// VGPR cap 128 via __launch_bounds__(512,2) [empirical: cap=2048/(arg2*waves)].
// Register diet vs R11: single bias buffer bA[8] (split refill after each
// subtile, ~0.5-0.9 iter flight) and exp2 in-place into acc (no p[16]).
// Fixed-max softmax -> k-half partials add exactly; in-block LDS combine.
__global__ __launch_bounds__(512, 2) void attn_kernel(
    const u16* __restrict__ qm, const u16* __restrict__ km,
    const u16* __restrict__ vtm, const float* __restrict__ bias,
    u16* __restrict__ aout) {
  __shared__ __align__(16) u16 smem[2][16384];  // dbuf x {K0,K1,V0,V1} x 8KB = 64KB
  const int tid = threadIdx.x;
  const int lane = tid & 63, wid = tid >> 6;
  const int lq = lane & 31, hi = lane >> 5;
  const int ws = wid & 3, hf = wid >> 2;  // q-strip, k-half
  // XCD swizzle: 512 blocks; xcd = lin&7 owns heads 2*xcd, 2*xcd+1
  const int lin = blockIdx.x;
  const int xcd = lin & 7, j = lin >> 3;  // j in [0,64)
  const int h = xcd * 2 + (j >> 5);
  const int rem = j & 31;
  const int b = rem >> 4, qb = rem & 15;
  const int q0w = qb * 128 + ws * 32;
  const size_t bh = (size_t)b * 16 + h;
  const u16* kg = km + bh * 2048 * 64;
  const u16* vg = vtm + bh * 64 * 2048;
  const u16* qbase = qm + (bh * 2048 + q0w) * 64;
  // lane's bias base: row (q0w+lq), col (hf*1024 + 4*hi)
  const float* brow = bias + ((size_t)h * 2048 + q0w + lq) * 2048 + hf * 1024 + 4 * hi;
  const int kofs = hf * 4096, vofs = 8192 + hf * 4096;

  bf16x8 qf[4];
#pragma unroll
  for (int i = 0; i < 4; ++i)
    qf[i] = *(const bf16x8*)&qbase[(size_t)lq * 64 + i * 16 + 8 * hi];

  f32x16 o[2];
#pragma unroll
  for (int r = 0; r < 16; ++r) { o[0][r] = 0.f; o[1][r] = 0.f; }
  float lsum = 0.f;

#define STAGE_TILE(gbase, rs, ldst)                                            \
  {                                                                            \
    int row = tid >> 3, pcol = tid & 7;                                        \
    int lcol = pcol ^ (row & 7);                                               \
    g2lds16((gbase) + (size_t)row * (rs) + lcol * 8, (ldst) + tid * 8);        \
  }

#define STAGE_ALL(P, kt_)                                                      \
  STAGE_TILE(kg + (size_t)((kt_) * 64) * 64, 64, &smem[P][0])                  \
  STAGE_TILE(kg + (size_t)(1024 + (kt_) * 64) * 64, 64, &smem[P][4096])        \
  STAGE_TILE(vg + (kt_) * 64, 2048, &smem[P][8192])                            \
  STAGE_TILE(vg + 1024 + (kt_) * 64, 2048, &smem[P][12288])

  // one 32-k subtile: QK^T(-32 acc) + bias + exp2 in-place + pack/swap + PV
#define SUBTILE(s_, PP)                                                        \
  {                                                                            \
    const u16* lKp = &smem[PP][kofs];                                          \
    const u16* lVp = &smem[PP][vofs];                                          \
    f32x16 acc;                                                                \
    _Pragma("unroll") for (int r = 0; r < 16; ++r) acc[r] = -32.0f;            \
    _Pragma("unroll") for (int i = 0; i < 4; ++i) {                            \
      int row = (s_) * 32 + lq;                                                \
      bf16x8 kf = *(const bf16x8*)&lKp[row * 64 + (((2 * i + hi) ^ (row & 7))) * 8]; \
      acc = MFMA32(kf, qf[i], acc);                                            \
    }                                                                          \
    _Pragma("unroll") for (int r = 0; r < 16; ++r) {                           \
      acc[r] = fmaf(bA[(s_) * 4 + (r >> 2)][r & 3], LOG2E, acc[r]);            \
      acc[r] = __builtin_amdgcn_exp2f(acc[r]);                                 \
      lsum += acc[r];                                                          \
    }                                                                          \
    unsigned c0 = cvt_pk_bf16(acc[0], acc[1]),   c1 = cvt_pk_bf16(acc[2], acc[3]);   \
    unsigned c2 = cvt_pk_bf16(acc[4], acc[5]),   c3 = cvt_pk_bf16(acc[6], acc[7]);   \
    unsigned c4 = cvt_pk_bf16(acc[8], acc[9]),   c5 = cvt_pk_bf16(acc[10], acc[11]); \
    unsigned c6 = cvt_pk_bf16(acc[12], acc[13]), c7 = cvt_pk_bf16(acc[14], acc[15]); \
    pl32swap(c0, c2); pl32swap(c1, c3);                                        \
    pl32swap(c4, c6); pl32swap(c5, c7);                                        \
    union { unsigned u[4]; bf16x8 v; } a0, a1;                                 \
    a0.u[0] = c0; a0.u[1] = c1; a0.u[2] = c2; a0.u[3] = c3;                    \
    a1.u[0] = c4; a1.u[1] = c5; a1.u[2] = c6; a1.u[3] = c7;                    \
    _Pragma("unroll") for (int dblk = 0; dblk < 2; ++dblk) {                   \
      int rowv = dblk * 32 + lq;                                               \
      bf16x8 v0 = *(const bf16x8*)&lVp[rowv * 64 + (((4 * (s_) + hi) ^ (rowv & 7))) * 8];     \
      bf16x8 v1 = *(const bf16x8*)&lVp[rowv * 64 + (((4 * (s_) + 2 + hi) ^ (rowv & 7))) * 8]; \
      o[dblk] = MFMA32(a0.v, v0, o[dblk]);                                     \
      o[dblk] = MFMA32(a1.v, v1, o[dblk]);                                     \
    }                                                                          \
  }

  // per iter: stage(t+1); SUBTILE0(t) [consumes bA 0..3] -> refill bA 0..3(t+1);
  // SUBTILE1(t) [consumes bA 4..7] -> refill bA 4..7(t+1); vmcnt(8); barrier.
#define ATTN_STEP(kt_, DOSTAGE, DOBIAS)                                        \
  {                                                                            \
    const int k0 = (kt_) * 64;                                                 \
    const int PP = (kt_) & 1;                                                  \
    if (DOSTAGE) { STAGE_ALL(PP ^ 1, (kt_) + 1) }                              \
    __builtin_amdgcn_sched_barrier(0);                                         \
    SUBTILE(0, PP)                                                             \
    if (DOBIAS) {                                                              \
      _Pragma("unroll") for (int gi = 0; gi < 4; ++gi)                         \
          bA[gi] = *(const float4*)(brow + k0 + 64 + gi * 8);                  \
    }                                                                          \
    __builtin_amdgcn_sched_barrier(0);                                         \
    SUBTILE(1, PP)                                                             \
    if (DOBIAS) {                                                              \
      _Pragma("unroll") for (int gi = 4; gi < 8; ++gi)                         \
          bA[gi] = *(const float4*)(brow + k0 + 64 + 32 + (gi & 3) * 8);       \
    }                                                                          \
    __builtin_amdgcn_sched_barrier(0);                                         \
    if (DOSTAGE && DOBIAS) { asm volatile("s_waitcnt vmcnt(8)" ::: "memory"); }\
    else                   { asm volatile("s_waitcnt vmcnt(0)" ::: "memory"); }\
    __builtin_amdgcn_sched_barrier(0);                                         \
    if (DOSTAGE) { __builtin_amdgcn_s_barrier(); }                             \
    __builtin_amdgcn_sched_barrier(0);                                         \
  }

  float4 bA[8];
  // prologue: stage k-tile 0 (both halves) -> buf0 (oldest 4), bias(0) -> bA
  STAGE_ALL(0, 0)
  __builtin_amdgcn_sched_barrier(0);
#pragma unroll
  for (int gi = 0; gi < 8; ++gi)
    bA[gi] = *(const float4*)(brow + (gi >> 2) * 32 + (gi & 3) * 8);
  __builtin_amdgcn_sched_barrier(0);
  asm volatile("s_waitcnt vmcnt(8)" ::: "memory");  // stage(0) landed
  __builtin_amdgcn_sched_barrier(0);
  __builtin_amdgcn_s_barrier();
  __builtin_amdgcn_sched_barrier(0);

#pragma unroll 1
  for (int kt = 0; kt < 15; ++kt) {
    ATTN_STEP(kt, 1, 1)
  }
  ATTN_STEP(15, 0, 0)
#undef ATTN_STEP
#undef SUBTILE
#undef STAGE_ALL
#undef STAGE_TILE

  // ---- in-block combine (staging LDS dead) ----
  lsum += __shfl_xor(lsum, 32, 64);  // full half-sum for q=lq
  __syncthreads();
  float* po = (float*)smem;          // 4 strips x 32 q x 64 d = 8192 f32
  float* pl = po + 8192;             // 4 strips x 32 q lsum
  if (hf == 1) {
#pragma unroll
    for (int r = 0; r < 16; ++r) {
      int qr = (r & 3) + 8 * (r >> 2) + 4 * hi;
      po[(ws * 32 + qr) * 64 + lq] = o[0][r];
      po[(ws * 32 + qr) * 64 + 32 + lq] = o[1][r];
    }
    pl[ws * 32 + lq] = lsum;
  }
  __syncthreads();
  if (hf == 0) {
    float l1 = pl[ws * 32 + lq];
    float linv = 1.0f / (lsum + l1);
#pragma unroll
    for (int r = 0; r < 16; ++r) {
      int qr = (r & 3) + 8 * (r >> 2) + 4 * hi;
      float lr = __shfl(linv, qr, 64);
      float v0 = o[0][r] + po[(ws * 32 + qr) * 64 + lq];
      float v1 = o[1][r] + po[(ws * 32 + qr) * 64 + 32 + lq];
      size_t base = ((size_t)b * 2048 + q0w + qr) * 1024 + h * 64 + lq;
      aout[base] = f2bf(v0 * lr);
      aout[base + 32] = f2bf(v1 * lr);
    }
  }
}

extern "C" void kernel_launch(void* const* d_in, const int* in_sizes, int n_in,
                              void* d_out, int out_size, void* d_ws, size_t ws_size,
                              hipStream_t stream) {
  const float* x  = (const float*)d_in[0];
  const float* rb = (const float*)d_in[1];
  const float* Wq = (const float*)d_in[2];
  const float* bq = (const float*)d_in[3];
  const float* Wk = (const float*)d_in[4];
  const float* bk = (const float*)d_in[5];
  const float* Wv = (const float*)d_in[6];
  const float* bv = (const float*)d_in[7];
  const float* Wo = (const float*)d_in[8];
  const float* bo = (const float*)d_in[9];
  float* out = (float*)d_out;
  char* ws = (char*)d_ws;

  u16* xb   = (u16*)(ws);                 // 8 MB  [4096,1024] bf16 (reused as aout)
  u16* W1b  = (u16*)(ws + (8 << 20));     // 6 MB  [3072,1024] bf16 (Wq|Wk|Wv)
  u16* Wob  = (u16*)(ws + (14 << 20));    // 2 MB  [1024,1024] bf16
  u16* qb   = (u16*)(ws + (16 << 20));    // 8 MB  [B,H,L,HD]
  u16* kb2  = (u16*)(ws + (24 << 20));    // 8 MB  [B,H,L,HD]
  u16* vtb  = (u16*)(ws + (32 << 20));    // 8 MB  [B,H,HD,L] (written by QKV GEMM)
  u16* aout = xb;                         // alias: xb dead after QKV GEMM

  cvt_all<<<4096, 256, 0, stream>>>(x, Wq, Wk, Wv, Wo, xb, W1b, Wob);
  gemm_bt<0><<<dim3(24, 32), 256, 0, stream>>>(xb, W1b, qb, kb2, vtb, bq, bk, bv,
                                               nullptr, nullptr);
  attn_kernel<<<512, 512, 0, stream>>>(qb, kb2, vtb, rb, aout);
  gemm_bt<1><<<dim3(8, 32), 256, 0, stream>>>(aout, Wob, nullptr, nullptr, nullptr,
                                              nullptr, nullptr, nullptr, out, bo);
}